// Round 14
// baseline (541.682 us; speedup 1.0000x reference)
//
#include <hip/hip_runtime.h>

// Spatially varying anisotropic 2D elastic wave sim, 384x384, 192 steps.
// Round 13: persistent kernel + per-EPOCH p2p neighbor flag sync.
// Sync-cost map so far (measured): per-step p2p ~20us (R4), grid.sync ~30us
// (R10), launch boundary ~6.4us (R8). This round: epoch-level p2p, predicted
// ~4-6us/boundary.
//  - R10 persistent structure (step loop measured identical to R8's ~260us)
//  - grid.sync -> 8-neighbor flag sync: owners store -> __syncthreads
//    (vmcnt drain) -> tid0 release flag=e+1 (AGENT) -> lanes 0..7 acquire-
//    poll neighbors >= e+1 -> __syncthreads. One check/epoch covers data-dep
//    AND anti-dep (neighbor flag >= e+1 implies it consumed buf[e&1]).
//  - coeffs loaded ONCE (R8 reloaded 16x); final-step LDS publish skipped
//  - flags live in unused C1.w lanes (setup re-zeroes; k1.w never consumed)
//  - 256 blocks = 1/CU -> co-residency guaranteed; bounded spin (no hang)

typedef float v2f __attribute__((ext_vector_type(2)));

#define NXg 384
#define NYg 384
#define NPT (NXg * NYg)
#define NFRAMES 48

#define OWN 24
#define HALO 12
#define TS 48
#define KSTEPS 12
#define NEPOCH 16
#define GB 16            // 16x16 grid
#define FLAG_STRIDE 512  // ints between flags (2KB); flag b at int b*512+3

#define H_   1e-4
#define DT_  5e-9
#define RHO_ 1610.0

#define B11_LO 5e10f
#define B11_HI 2.5e11f
#define B22_LO 5e9f
#define B22_HI 5e10f
#define B12_LO 5e9f
#define B12_HI 5e10f
#define B16_LO 0.0f
#define B16_HI 6e10f
#define B26_LO 0.0f
#define B26_HI 2e10f
#define B66_LO 5e9f
#define B66_HI 3e10f

static __device__ __constant__ float kScale  = (float)(DT_ * DT_ / (H_ * H_) / RHO_);
static __device__ __constant__ float kSrcScl = (float)(DT_ * DT_ / RHO_);

__device__ __forceinline__ float clipf(float v, float lo, float hi) {
    return fminf(fmaxf(v, lo), hi);
}
__device__ __forceinline__ v2f vfma(v2f a, v2f b, v2f c) {
    return __builtin_elementwise_fma(a, b, c);
}
__device__ __forceinline__ v2f vbc(float s) { v2f r; r[0] = s; r[1] = s; return r; }
__device__ __forceinline__ v2f vswap(v2f a) { return __builtin_shufflevector(a, a, 1, 0); }

// barrier that only waits LDS (no vmcnt drain)
#define LDS_BARRIER() asm volatile("s_waitcnt lgkmcnt(0)\n\ts_barrier" ::: "memory")

// ws float layout:
// [0..4NPT):    C0 = float4{A11, A22, A12p66, A16}  (pre-scaled)
// [4NPT..8NPT): C1 = float4{A26, A66, GS, 0}   (.w lanes double as flags)
// [8NPT..12NPT):  state buf0: float4{cur.x, cur.y, old.x, old.y}
// [12NPT..16NPT): state buf1

__global__ __launch_bounds__(256)
void setup_kernel(const float* __restrict__ lc11, const float* __restrict__ lc12,
                  const float* __restrict__ lc16, const float* __restrict__ lc22,
                  const float* __restrict__ lc26, const float* __restrict__ lc66,
                  const float* __restrict__ gauss, float* __restrict__ ws) {
    int i = blockIdx.x * blockDim.x + threadIdx.x;
    if (i >= NPT) return;
    float C11 = clipf(expf(lc11[i]), B11_LO, B11_HI);
    float C12 = clipf(expf(lc12[i]), B12_LO, B12_HI);
    float C16 = clipf(expf(lc16[i]), B16_LO, B16_HI);
    float C22 = clipf(expf(lc22[i]), B22_LO, B22_HI);
    float C26 = clipf(expf(lc26[i]), B26_LO, B26_HI);
    float C66 = clipf(expf(lc66[i]), B66_LO, B66_HI);
    float s = kScale;
    float4* C0 = (float4*)ws;
    float4* C1 = (float4*)(ws + 4 * (size_t)NPT);
    C0[i] = make_float4(C11 * s, C22 * s, (C12 + C66) * s, C16 * s);
    C1[i] = make_float4(C26 * s, C66 * s, gauss[i] * kSrcScl, 0.0f);  // .w=flag=0
    float4* s0 = (float4*)(ws + 8 * (size_t)NPT);
    float4* s1 = (float4*)(ws + 12 * (size_t)NPT);
    s0[i] = make_float4(0.0f, 0.0f, 0.0f, 0.0f);
    s1[i] = make_float4(0.0f, 0.0f, 0.0f, 0.0f);
}

__global__ __launch_bounds__(256, 1)
void persist_kernel(float* __restrict__ ws, const float* __restrict__ sig,
                    float* __restrict__ out) {
    __shared__ v2f sb[2][TS][TS + 1];

    const int tid = threadIdx.x;
    const int tx = tid >> 4;
    const int ty = tid & 15;
    const int r0 = 3 * tx;
    const int c0 = 3 * ty;
    const int bx = (int)blockIdx.x;
    const int by = (int)blockIdx.y;
    const int gx0 = by * OWN - HALO;
    const int gy0 = bx * OWN - HALO;

    const float4* __restrict__ C0 = (const float4*)ws;
    const float4* __restrict__ C1 = (const float4*)(ws + 4 * (size_t)NPT);
    float4* __restrict__ st[2];
    st[0] = (float4*)(ws + 8 * (size_t)NPT);
    st[1] = (float4*)(ws + 12 * (size_t)NPT);
    int* __restrict__ flags = (int*)(ws + 4 * (size_t)NPT);  // .w lanes

    v2f cur[9], old_[9];
    v2f ca[9], cb[9];                       // {A11,A66}, {A66,A22}
    float a12p66[9], a16[9], a26[9], gs[9];
    int gidx[9];
    bool dom[9];

    // ---- one-time coeff load (registers for all 192 steps) ----
#pragma unroll
    for (int i = 0; i < 3; ++i) {
#pragma unroll
        for (int j = 0; j < 3; ++j) {
            int p = i * 3 + j;
            int gx = gx0 + r0 + i;
            int gy = gy0 + c0 + j;
            bool d = (unsigned)gx < (unsigned)NXg && (unsigned)gy < (unsigned)NYg;
            int g = d ? gx * NYg + gy : 0;
            gidx[p] = g; dom[p] = d;
            float4 k0 = d ? C0[g] : make_float4(0, 0, 0, 0);
            float4 k1 = d ? C1[g] : make_float4(0, 0, 0, 0);   // .w ignored
            v2f t; t[0] = k0.x; t[1] = k1.y; ca[p] = t;   // {A11, A66}
            v2f u; u[0] = k1.y; u[1] = k0.y; cb[p] = u;   // {A66, A22}
            a12p66[p] = k0.z; a16[p] = k0.w; a26[p] = k1.x; gs[p] = k1.z;
            cur[p] = vbc(0.0f);
            old_[p] = vbc(0.0f);
        }
    }

    // neighbor flag indices for poller lanes 0..7
    int nbFlag = -1;
    if (tid < 8) {
        const int dr[8] = {-1, -1, -1,  0, 0,  1, 1, 1};
        const int dc[8] = {-1,  0,  1, -1, 1, -1, 0, 1};
        int nby = by + dr[tid];
        int nbx = bx + dc[tid];
        if (nbx >= 0 && nbx < GB && nby >= 0 && nby < GB)
            nbFlag = (nby * GB + nbx) * FLAG_STRIDE + 3;
    }
    const int myFlag = (by * GB + bx) * FLAG_STRIDE + 3;

    // clamped halo coords (trapezoid garbage-tolerance at staging rim)
    const int rm = (r0 > 0) ? r0 - 1 : 0;
    const int rp = (r0 + 3 < TS) ? r0 + 3 : TS - 1;
    const int cm = (c0 > 0) ? c0 - 1 : 0;
    const int cp = (c0 + 3 < TS) ? c0 + 3 : TS - 1;

    const bool owned = (tx >= 4) && (tx < 12) && (ty >= 4) && (ty < 12);

    v2f c20; c20[0] = 2.0f; c20[1] = 0.0f;
    v2f c02; c02[0] = 0.0f; c02[1] = 2.0f;
    const v2f m2 = vbc(-2.0f);
    const v2f qt = vbc(0.25f);
    const v2f two = vbc(2.0f);

#pragma unroll 1
    for (int e = 0; e < NEPOCH; ++e) {
        // ---- epoch prologue: halo threads reload state (owners keep regs)
        // epoch e reads buf[(e+1)&1]; epoch 0 reads buf1 == zeros.
        if (!owned) {
            const float4* __restrict__ rs = st[(e + 1) & 1];
#pragma unroll
            for (int p = 0; p < 9; ++p) {
                float4 s4 = dom[p] ? rs[gidx[p]] : make_float4(0, 0, 0, 0);
                v2f c; c[0] = s4.x; c[1] = s4.y;
                v2f o; o[0] = s4.z; o[1] = s4.w;
                cur[p] = c; old_[p] = o;
            }
        }
        const int t0 = e * KSTEPS;
        float sigv[KSTEPS];
#pragma unroll
        for (int k = 0; k < KSTEPS; ++k) sigv[k] = sig[t0 + k];

        // publish initial values into buffer 0
#pragma unroll
        for (int i = 0; i < 3; ++i)
#pragma unroll
            for (int j = 0; j < 3; ++j)
                sb[0][r0 + i][c0 + j] = cur[i * 3 + j];
        LDS_BARRIER();

#pragma unroll 1
        for (int s = 1; s <= KSTEPS; ++s) {
            const v2f (*rb)[TS + 1] = sb[(s - 1) & 1];
            v2f (*wb)[TS + 1] = sb[s & 1];
            v2f vsig; vsig[0] = 0.0f; vsig[1] = sigv[s - 1];

            // assemble 5x5 v2f window: own 3x3 from regs + 16 halo b64 reads
            v2f v[5][5];
#pragma unroll
            for (int i = 0; i < 3; ++i)
#pragma unroll
                for (int j = 0; j < 3; ++j)
                    v[i + 1][j + 1] = cur[i * 3 + j];
            v[0][0] = rb[rm][cm];  v[0][4] = rb[rm][cp];
            v[4][0] = rb[rp][cm];  v[4][4] = rb[rp][cp];
#pragma unroll
            for (int j = 0; j < 3; ++j) {
                v[0][j + 1] = rb[rm][c0 + j];
                v[4][j + 1] = rb[rp][c0 + j];
                v[j + 1][0] = rb[r0 + j][cm];
                v[j + 1][4] = rb[r0 + j][cp];
            }

            // horizontal differences shared across the 9 points
            v2f dh[5][3];
#pragma unroll
            for (int i = 0; i < 5; ++i)
#pragma unroll
                for (int j = 0; j < 3; ++j)
                    dh[i][j] = v[i][j + 2] - v[i][j];

#pragma unroll
            for (int i = 0; i < 3; ++i)
#pragma unroll
                for (int j = 0; j < 3; ++j) {
                    int p = i * 3 + j;
                    v2f c = v[i + 1][j + 1];
                    v2f sxx = vfma(m2, c, v[i][j + 1] + v[i + 2][j + 1]);
                    v2f syy = vfma(m2, c, v[i + 1][j] + v[i + 1][j + 2]);
                    v2f sxy = qt * (dh[i + 2][j] - dh[i][j]);

                    v2f t4 = vfma(c20, vbc(sxy[0]), vswap(sxx));
                    v2f t5 = vfma(c02, vbc(sxy[1]), vswap(syy));
                    v2f Lv = ca[p] * sxx;
                    Lv = vfma(cb[p], syy, Lv);
                    Lv = vfma(vbc(a12p66[p]), vswap(sxy), Lv);
                    Lv = vfma(vbc(a16[p]), t4, Lv);
                    Lv = vfma(vbc(a26[p]), t5, Lv);
                    Lv = vfma(vsig, vbc(gs[p]), Lv);   // {lux, sig*gs + luy}
                    v2f n = vfma(two, c, Lv) - old_[p];
                    old_[p] = c;
                    cur[p] = n;
                }

            // frame output at global t = t0 + s - 1; t%4==3 <=> s%4==0
            // (fire-and-forget: step barrier does NOT drain vmcnt)
            if ((s & 3) == 0 && owned) {
                int f = 3 * e + (s >> 2) - 1;
                float* oux = out + (size_t)f * NPT;
                float* ouy = out + (size_t)(NFRAMES + f) * NPT;
#pragma unroll
                for (int p = 0; p < 9; ++p) {
                    oux[gidx[p]] = cur[p][0];
                    ouy[gidx[p]] = cur[p][1];
                }
            }

            // publish for next step; skip on final step (nobody reads it)
            if (s < KSTEPS) {
#pragma unroll
                for (int i = 0; i < 3; ++i)
#pragma unroll
                    for (int j = 0; j < 3; ++j)
                        wb[r0 + i][c0 + j] = cur[i * 3 + j];
                LDS_BARRIER();
            }
        }

        // ---- epoch boundary: publish state, release flag, poll neighbors
        if (e + 1 < NEPOCH) {
            if (owned) {
                float4* __restrict__ wsbuf = st[e & 1];
#pragma unroll
                for (int p = 0; p < 9; ++p)
                    wsbuf[gidx[p]] = make_float4(cur[p][0], cur[p][1],
                                                 old_[p][0], old_[p][1]);
            }
            __syncthreads();   // all waves' stores drained (vmcnt 0)
            if (tid == 0)
                __hip_atomic_store(&flags[myFlag], e + 1, __ATOMIC_RELEASE,
                                   __HIP_MEMORY_SCOPE_AGENT);
            if (nbFlag >= 0) {
                long spin = 0;
                while (__hip_atomic_load(&flags[nbFlag], __ATOMIC_ACQUIRE,
                                         __HIP_MEMORY_SCOPE_AGENT) < e + 1) {
                    __builtin_amdgcn_s_sleep(1);
                    if (++spin > 100000000L) break;   // hang guard
                }
            }
            __syncthreads();   // hold all threads until polls complete
        }
    }
}

extern "C" void kernel_launch(void* const* d_in, const int* in_sizes, int n_in,
                              void* d_out, int out_size, void* d_ws, size_t ws_size,
                              hipStream_t stream) {
    const float* lc11  = (const float*)d_in[0];
    const float* lc12  = (const float*)d_in[1];
    const float* lc16  = (const float*)d_in[2];
    const float* lc22  = (const float*)d_in[3];
    const float* lc26  = (const float*)d_in[4];
    const float* lc66  = (const float*)d_in[5];
    const float* gauss = (const float*)d_in[6];
    const float* sig   = (const float*)d_in[7];

    float* ws  = (float*)d_ws;
    float* out = (float*)d_out;

    setup_kernel<<<(NPT + 255) / 256, 256, 0, stream>>>(lc11, lc12, lc16, lc22,
                                                        lc26, lc66, gauss, ws);

    dim3 grid(GB, GB);  // 16x16 = 256 blocks, 1 per CU, all co-resident
    persist_kernel<<<grid, 256, 0, stream>>>(ws, sig, out);
}